// Round 6
// baseline (728.580 us; speedup 1.0000x reference)
//
#include <hip/hip_runtime.h>

#define NN 50000
#define NE 800000
#define NS 4
#define NT (NS * NN)          // 200000
#define D 128
#define SB2 782               // ceil(NT/256)
#define EW_SCALE 262144.0f    // 2^18 fixed-point for packed degree
#define EW_INV (1.0f / 262144.0f)

typedef unsigned long long ull;
typedef __attribute__((ext_vector_type(8))) short bf16x8;
typedef __attribute__((ext_vector_type(4))) float f32x4;

__device__ __forceinline__ unsigned short f2bf(float f) {
  unsigned int u = __float_as_uint(f);
  u += 0x7fffu + ((u >> 16) & 1u);  // RNE
  return (unsigned short)(u >> 16);
}
__device__ __forceinline__ float bf2f(unsigned short h) {
  return __uint_as_float((unsigned int)h << 16);
}

// ---------------- GEMM: H0h[M x D] (bf16) = X[M x D] @ W[D x D] ----------------
// ws-staged VALU GEMM (x is fp32; bf16 MFMA would add input-rounding error).
// NOTE: runs AFTER unpack_scan_k (H0h aliases pack8's storage).

__global__ __launch_bounds__(256) void gemm_plain_bf16out(
    const float* __restrict__ X, const float* __restrict__ W,
    unsigned short* __restrict__ O, int M) {
  __shared__ float xs[64 * 130];
  __shared__ float ws[32 * 128];
  const int tid = threadIdx.x;
  const int r0 = blockIdx.x * 64;
  for (int i = tid; i < 64 * 64; i += 256) {
    int row = i >> 6, kh = i & 63;
    float2 v = make_float2(0.f, 0.f);
    int gr = r0 + row;
    if (gr < M) v = *(const float2*)&X[(size_t)gr * D + kh * 2];
    *(float2*)&xs[row * 130 + kh * 2] = v;
  }
  const int tx = tid & 15, ty = tid >> 4;
  const int c0 = tx * 4;        // cols c0..c0+3
  const int c1 = 64 + tx * 4;   // cols c1..c1+3
  float acc[4][8];
#pragma unroll
  for (int i = 0; i < 4; i++)
#pragma unroll
    for (int j = 0; j < 8; j++) acc[i][j] = 0.f;

  for (int kc = 0; kc < 4; kc++) {
    __syncthreads();
    for (int i = tid; i < 32 * 32; i += 256) {
      ((float4*)ws)[i] = ((const float4*)(W + kc * 32 * D))[i];
    }
    __syncthreads();
#pragma unroll 4
    for (int k2 = 0; k2 < 32; k2++) {
      const int k = kc * 32 + k2;
      float a[4];
#pragma unroll
      for (int j = 0; j < 4; j++) a[j] = xs[(ty * 4 + j) * 130 + k];
      float4 b0 = *(const float4*)&ws[k2 * 128 + c0];
      float4 b1 = *(const float4*)&ws[k2 * 128 + c1];
      float b[8] = {b0.x, b0.y, b0.z, b0.w, b1.x, b1.y, b1.z, b1.w};
#pragma unroll
      for (int i = 0; i < 4; i++)
#pragma unroll
        for (int j = 0; j < 8; j++) acc[i][j] += a[i] * b[j];
    }
  }
#pragma unroll
  for (int i = 0; i < 4; i++) {
    int gr = r0 + ty * 4 + i;
    if (gr < M) {
      ushort4 o0, o1;
      o0.x = f2bf(acc[i][0]); o0.y = f2bf(acc[i][1]);
      o0.z = f2bf(acc[i][2]); o0.w = f2bf(acc[i][3]);
      o1.x = f2bf(acc[i][4]); o1.y = f2bf(acc[i][5]);
      o1.z = f2bf(acc[i][6]); o1.w = f2bf(acc[i][7]);
      *(ushort4*)&O[(size_t)gr * D + c0] = o0;
      *(ushort4*)&O[(size_t)gr * D + c1] = o1;
    }
  }
}

// ---------------- W1 fragment prep: hi/lo bf16 split, MFMA lane order ----------
__global__ __launch_bounds__(256) void prep_w1_k(const float* __restrict__ W,
                                                 unsigned short* __restrict__ Wsw) {
  int idx = blockIdx.x * 256 + threadIdx.x;  // 16384 total
  int j = idx & 7, lane = (idx >> 3) & 63, s = (idx >> 9) & 3, bn = idx >> 11;
  float v = W[(s * 32 + ((lane >> 4) * 8) + j) * D + bn * 16 + (lane & 15)];
  unsigned short hi = f2bf(v);
  float lo = v - bf2f(hi);
  Wsw[idx] = hi;
  Wsw[16384 + idx] = f2bf(lo);
}

// ---------------- in-place MFMA GEMM: Zh[t] <- bf16(Zh[t] @ W1) ----------------
__global__ __launch_bounds__(256) void gemm_inplace_mfma_k(
    unsigned short* __restrict__ ZhA, const unsigned short* __restrict__ Wsw) {
  const int t = blockIdx.y;
  unsigned short* Z = ZhA + (size_t)t * NN * D;
  const int tid = threadIdx.x;
  const int wv = tid >> 6, l = tid & 63;
  const int r0 = blockIdx.x * 64 + wv * 16;
  const int mrow = r0 + (l & 15);
  const int arow = mrow < NN ? mrow : NN - 1;
  bf16x8 a[4];
#pragma unroll
  for (int s = 0; s < 4; s++)
    a[s] = *(const bf16x8*)&Z[(size_t)arow * D + s * 32 + (l >> 4) * 8];
  const int orow0 = r0 + (l >> 4) * 4;
#pragma unroll
  for (int bn = 0; bn < 8; bn++) {
    f32x4 acc = {0.f, 0.f, 0.f, 0.f};
#pragma unroll
    for (int s = 0; s < 4; s++) {
      bf16x8 blo = *(const bf16x8*)&Wsw[16384 + ((bn * 4 + s) * 64 + l) * 8];
      bf16x8 bhi = *(const bf16x8*)&Wsw[((bn * 4 + s) * 64 + l) * 8];
      acc = __builtin_amdgcn_mfma_f32_16x16x32_bf16(a[s], blo, acc, 0, 0, 0);
      acc = __builtin_amdgcn_mfma_f32_16x16x32_bf16(a[s], bhi, acc, 0, 0, 0);
    }
    const int col = bn * 16 + (l & 15);
#pragma unroll
    for (int i = 0; i < 4; i++) {
      int row = orow0 + i;
      if (row < NN) Z[(size_t)row * D + col] = f2bf(acc[i]);
    }
  }
}

// ---------------- CSR build, batched over all 4 scales ----------------

__global__ __launch_bounds__(256) void initp_k(ull* __restrict__ packed, int n) {
  int i = blockIdx.x * 256 + threadIdx.x;
  if (i < n) packed[i] = 0ULL;
}

// grid (782, NS), 4 edges/thread, 8-way privatized histogram: copy = bx & 7.
// Same RMW count, 8x more distinct cachelines -> per-line serialization / 8.
// pos (old>>32) = rank within (copy, t, dst).
__global__ __launch_bounds__(256) void countpos_all_k(const int* __restrict__ ei,
                                                      const float* __restrict__ ewA,
                                                      ull* __restrict__ pack8,
                                                      int* __restrict__ posA) {
  const int t = blockIdx.y;
  const int e0 = blockIdx.x * 1024 + threadIdx.x;
  const size_t cOff = (size_t)(blockIdx.x & 7) * NT;
  const int* dst = ei + (size_t)t * 2 * NE + NE;
  const float* ew = ewA + (size_t)t * NE;
  int d[4];
  float w[4];
  bool va[4];
#pragma unroll
  for (int q = 0; q < 4; q++) {
    int e = e0 + q * 256;
    va[q] = e < NE;
    d[q] = 0;
    w[q] = 0.f;
    if (va[q]) {
      d[q] = dst[e];
      w[q] = ew[e];
    }
  }
  ull old[4];
#pragma unroll
  for (int q = 0; q < 4; q++) {
    if (va[q]) {
      ull add = (1ULL << 32) | (ull)__float2uint_rn(w[q] * EW_SCALE);
      old[q] = atomicAdd(&pack8[cOff + t * NN + d[q]], add);
    }
  }
#pragma unroll
  for (int q = 0; q < 4; q++) {
    if (va[q]) posA[(size_t)t * NE + e0 + q * 256] = (int)(old[q] >> 32);
  }
}

// unpack 8 copies + per-copy exclusive base + per-block partial sum. grid SB2.
__global__ __launch_bounds__(256) void unpack_scan_k(const ull* __restrict__ pack8,
                                                     float* __restrict__ dinvA,
                                                     int* __restrict__ cntA,
                                                     unsigned short* __restrict__ cbase8,
                                                     int* __restrict__ partial) {
  __shared__ int sm[256];
  const int tid = threadIdx.x;
  const int i = blockIdx.x * 256 + tid;
  int c = 0;
  if (i < NT) {
    unsigned int wsum = 0;
    int run = 0;
#pragma unroll
    for (int k = 0; k < 8; k++) {
      ull p = pack8[(size_t)k * NT + i];
      cbase8[(size_t)k * NT + i] = (unsigned short)run;
      run += (int)(p >> 32);
      wsum += (unsigned int)(p & 0xffffffffULL);
    }
    c = run;
    cntA[i] = c;
    float deg = 1.0f + (float)wsum * EW_INV;
    dinvA[i] = rsqrtf(deg);
  }
  sm[tid] = c;
  __syncthreads();
  for (int off = 128; off > 0; off >>= 1) {
    if (tid < off) sm[tid] += sm[tid + off];
    __syncthreads();
  }
  if (tid == 0) partial[blockIdx.x] = sm[0];
}

// single block: exclusive scan of SB2 partials (chunked serial + block scan)
__global__ __launch_bounds__(256) void scan_top_k(const int* __restrict__ partial,
                                                  int* __restrict__ poffs, int nb) {
  __shared__ int sm[256];
  const int t = threadIdx.x;
  const int chunk = (nb + 255) >> 8;
  const int lo = t * chunk;
  const int hi = min(lo + chunk, nb);
  int s = 0;
  for (int i = lo; i < hi; i++) s += partial[i];
  sm[t] = s;
  __syncthreads();
  for (int off = 1; off < 256; off <<= 1) {
    int u = (t >= off) ? sm[t - off] : 0;
    __syncthreads();
    sm[t] += u;
    __syncthreads();
  }
  int run = sm[t] - s;  // exclusive
  for (int i = lo; i < hi; i++) {
    poffs[i] = run;
    run += partial[i];
  }
}

__global__ __launch_bounds__(256) void scan_write_k(const int* __restrict__ cntA,
                                                    const int* __restrict__ poffs,
                                                    int* __restrict__ offsA) {
  __shared__ int sm[256];
  const int t = threadIdx.x;
  const int i = blockIdx.x * 256 + t;
  int v = (i < NT) ? cntA[i] : 0;
  sm[t] = v;
  __syncthreads();
  for (int off = 1; off < 256; off <<= 1) {
    int u = (t >= off) ? sm[t - off] : 0;
    __syncthreads();
    sm[t] += u;
    __syncthreads();
  }
  if (i < NT) offsA[i] = poffs[blockIdx.x] + sm[t] - v;
}

// grid (3125, NS): slot = offs[d] + cbase8[copy][d] + pos, copy = (e>>10)&7.
__global__ __launch_bounds__(256) void fill_all_k(const int* __restrict__ ei,
                                                  const float* __restrict__ ewA,
                                                  const float* __restrict__ dinvA,
                                                  const int* __restrict__ offsA,
                                                  const int* __restrict__ posA,
                                                  const unsigned short* __restrict__ cbase8,
                                                  int2* __restrict__ eeA) {
  const int t = blockIdx.y;
  const int e = blockIdx.x * 256 + threadIdx.x;
  if (e < NE) {
    const int* src = ei + (size_t)t * 2 * NE;
    const int* dst = src + NE;
    int s = src[e], d = dst[e];
    const int base = t * NN + d;
    const size_t cOff = (size_t)((e >> 10) & 7) * NT;
    float w = ewA[(size_t)t * NE + e] * dinvA[t * NN + s] * dinvA[base];
    int slot = offsA[base] + (int)cbase8[cOff + base] + posA[(size_t)t * NE + e];
    eeA[slot] = make_int2(s, __float_as_int(w));
  }
}

// ---------------- layer-1 gather, batched: grid (6250, NS) ----------------
__global__ __launch_bounds__(256) void gather1_all_k(
    const unsigned short* __restrict__ H, const int* __restrict__ offsA,
    const int* __restrict__ cntA, const int2* __restrict__ eeA,
    const float* __restrict__ dinvA, const float* __restrict__ bias,
    const float* __restrict__ pa, unsigned short* __restrict__ ZhA) {
  const int t = blockIdx.y;
  int g = blockIdx.x * 256 + threadIdx.x;
  int wid = g >> 5;
  int lane = g & 31;
  if (wid >= NN) return;
  const int base = t * NN + wid;
  const int st = offsA[base];
  const int len = cntA[base];
  const int c = lane * 4;
  float ax = 0.f, ay = 0.f, az = 0.f, aw = 0.f;
  int j = 0;
  for (; j + 8 <= len; j += 8) {
    int2 p0 = eeA[st + j];
    int2 p1 = eeA[st + j + 1];
    int2 p2 = eeA[st + j + 2];
    int2 p3 = eeA[st + j + 3];
    int2 p4 = eeA[st + j + 4];
    int2 p5 = eeA[st + j + 5];
    int2 p6 = eeA[st + j + 6];
    int2 p7 = eeA[st + j + 7];
    ushort4 v0 = *(const ushort4*)&H[(size_t)p0.x * D + c];
    ushort4 v1 = *(const ushort4*)&H[(size_t)p1.x * D + c];
    ushort4 v2 = *(const ushort4*)&H[(size_t)p2.x * D + c];
    ushort4 v3 = *(const ushort4*)&H[(size_t)p3.x * D + c];
    ushort4 v4 = *(const ushort4*)&H[(size_t)p4.x * D + c];
    ushort4 v5 = *(const ushort4*)&H[(size_t)p5.x * D + c];
    ushort4 v6 = *(const ushort4*)&H[(size_t)p6.x * D + c];
    ushort4 v7 = *(const ushort4*)&H[(size_t)p7.x * D + c];
    float w0 = __int_as_float(p0.y), w1 = __int_as_float(p1.y);
    float w2 = __int_as_float(p2.y), w3 = __int_as_float(p3.y);
    float w4 = __int_as_float(p4.y), w5 = __int_as_float(p5.y);
    float w6 = __int_as_float(p6.y), w7 = __int_as_float(p7.y);
    ax += w0 * bf2f(v0.x) + w1 * bf2f(v1.x) + w2 * bf2f(v2.x) + w3 * bf2f(v3.x);
    ay += w0 * bf2f(v0.y) + w1 * bf2f(v1.y) + w2 * bf2f(v2.y) + w3 * bf2f(v3.y);
    az += w0 * bf2f(v0.z) + w1 * bf2f(v1.z) + w2 * bf2f(v2.z) + w3 * bf2f(v3.z);
    aw += w0 * bf2f(v0.w) + w1 * bf2f(v1.w) + w2 * bf2f(v2.w) + w3 * bf2f(v3.w);
    ax += w4 * bf2f(v4.x) + w5 * bf2f(v5.x) + w6 * bf2f(v6.x) + w7 * bf2f(v7.x);
    ay += w4 * bf2f(v4.y) + w5 * bf2f(v5.y) + w6 * bf2f(v6.y) + w7 * bf2f(v7.y);
    az += w4 * bf2f(v4.z) + w5 * bf2f(v5.z) + w6 * bf2f(v6.z) + w7 * bf2f(v7.z);
    aw += w4 * bf2f(v4.w) + w5 * bf2f(v5.w) + w6 * bf2f(v6.w) + w7 * bf2f(v7.w);
  }
  for (; j + 4 <= len; j += 4) {
    int2 p0 = eeA[st + j];
    int2 p1 = eeA[st + j + 1];
    int2 p2 = eeA[st + j + 2];
    int2 p3 = eeA[st + j + 3];
    ushort4 v0 = *(const ushort4*)&H[(size_t)p0.x * D + c];
    ushort4 v1 = *(const ushort4*)&H[(size_t)p1.x * D + c];
    ushort4 v2 = *(const ushort4*)&H[(size_t)p2.x * D + c];
    ushort4 v3 = *(const ushort4*)&H[(size_t)p3.x * D + c];
    float w0 = __int_as_float(p0.y), w1 = __int_as_float(p1.y);
    float w2 = __int_as_float(p2.y), w3 = __int_as_float(p3.y);
    ax += w0 * bf2f(v0.x) + w1 * bf2f(v1.x) + w2 * bf2f(v2.x) + w3 * bf2f(v3.x);
    ay += w0 * bf2f(v0.y) + w1 * bf2f(v1.y) + w2 * bf2f(v2.y) + w3 * bf2f(v3.y);
    az += w0 * bf2f(v0.z) + w1 * bf2f(v1.z) + w2 * bf2f(v2.z) + w3 * bf2f(v3.z);
    aw += w0 * bf2f(v0.w) + w1 * bf2f(v1.w) + w2 * bf2f(v2.w) + w3 * bf2f(v3.w);
  }
  for (; j < len; j++) {
    int2 p = eeA[st + j];
    float w = __int_as_float(p.y);
    ushort4 v = *(const ushort4*)&H[(size_t)p.x * D + c];
    ax += w * bf2f(v.x);
    ay += w * bf2f(v.y);
    az += w * bf2f(v.z);
    aw += w * bf2f(v.w);
  }
  float dv = dinvA[base];
  float d2 = dv * dv;
  ushort4 h = *(const ushort4*)&H[(size_t)wid * D + c];
  ax += d2 * bf2f(h.x) + bias[c];
  ay += d2 * bf2f(h.y) + bias[c + 1];
  az += d2 * bf2f(h.z) + bias[c + 2];
  aw += d2 * bf2f(h.w) + bias[c + 3];
  ax = ax > 0.f ? ax : pa[c] * ax;
  ay = ay > 0.f ? ay : pa[c + 1] * ay;
  az = az > 0.f ? az : pa[c + 2] * az;
  aw = aw > 0.f ? aw : pa[c + 3] * aw;
  ushort4 o;
  o.x = f2bf(ax); o.y = f2bf(ay); o.z = f2bf(az); o.w = f2bf(aw);
  *(ushort4*)&ZhA[(size_t)t * NN * D + (size_t)wid * D + c] = o;
}

// ---------------- layer-2 gather, batched: grid (6250, NS) ----------------
__global__ __launch_bounds__(256) void gather2_all_k(
    const unsigned short* __restrict__ YA, const int* __restrict__ offsA,
    const int* __restrict__ cntA, const int2* __restrict__ eeA,
    const float* __restrict__ dinvA, const float* __restrict__ bias,
    const float* __restrict__ pa, float* __restrict__ out) {
  const int t = blockIdx.y;
  int g = blockIdx.x * 256 + threadIdx.x;
  int wid = g >> 5;
  int lane = g & 31;
  if (wid >= NN) return;
  const unsigned short* Y = YA + (size_t)t * NN * D;
  const int base = t * NN + wid;
  const int st = offsA[base];
  const int len = cntA[base];
  const int c = lane * 4;
  float ax = 0.f, ay = 0.f, az = 0.f, aw = 0.f;
  int j = 0;
  for (; j + 8 <= len; j += 8) {
    int2 p0 = eeA[st + j];
    int2 p1 = eeA[st + j + 1];
    int2 p2 = eeA[st + j + 2];
    int2 p3 = eeA[st + j + 3];
    int2 p4 = eeA[st + j + 4];
    int2 p5 = eeA[st + j + 5];
    int2 p6 = eeA[st + j + 6];
    int2 p7 = eeA[st + j + 7];
    ushort4 v0 = *(const ushort4*)&Y[(size_t)p0.x * D + c];
    ushort4 v1 = *(const ushort4*)&Y[(size_t)p1.x * D + c];
    ushort4 v2 = *(const ushort4*)&Y[(size_t)p2.x * D + c];
    ushort4 v3 = *(const ushort4*)&Y[(size_t)p3.x * D + c];
    ushort4 v4 = *(const ushort4*)&Y[(size_t)p4.x * D + c];
    ushort4 v5 = *(const ushort4*)&Y[(size_t)p5.x * D + c];
    ushort4 v6 = *(const ushort4*)&Y[(size_t)p6.x * D + c];
    ushort4 v7 = *(const ushort4*)&Y[(size_t)p7.x * D + c];
    float w0 = __int_as_float(p0.y), w1 = __int_as_float(p1.y);
    float w2 = __int_as_float(p2.y), w3 = __int_as_float(p3.y);
    float w4 = __int_as_float(p4.y), w5 = __int_as_float(p5.y);
    float w6 = __int_as_float(p6.y), w7 = __int_as_float(p7.y);
    ax += w0 * bf2f(v0.x) + w1 * bf2f(v1.x) + w2 * bf2f(v2.x) + w3 * bf2f(v3.x);
    ay += w0 * bf2f(v0.y) + w1 * bf2f(v1.y) + w2 * bf2f(v2.y) + w3 * bf2f(v3.y);
    az += w0 * bf2f(v0.z) + w1 * bf2f(v1.z) + w2 * bf2f(v2.z) + w3 * bf2f(v3.z);
    aw += w0 * bf2f(v0.w) + w1 * bf2f(v1.w) + w2 * bf2f(v2.w) + w3 * bf2f(v3.w);
    ax += w4 * bf2f(v4.x) + w5 * bf2f(v5.x) + w6 * bf2f(v6.x) + w7 * bf2f(v7.x);
    ay += w4 * bf2f(v4.y) + w5 * bf2f(v5.y) + w6 * bf2f(v6.y) + w7 * bf2f(v7.y);
    az += w4 * bf2f(v4.z) + w5 * bf2f(v5.z) + w6 * bf2f(v6.z) + w7 * bf2f(v7.z);
    aw += w4 * bf2f(v4.w) + w5 * bf2f(v5.w) + w6 * bf2f(v6.w) + w7 * bf2f(v7.w);
  }
  for (; j + 4 <= len; j += 4) {
    int2 p0 = eeA[st + j];
    int2 p1 = eeA[st + j + 1];
    int2 p2 = eeA[st + j + 2];
    int2 p3 = eeA[st + j + 3];
    ushort4 v0 = *(const ushort4*)&Y[(size_t)p0.x * D + c];
    ushort4 v1 = *(const ushort4*)&Y[(size_t)p1.x * D + c];
    ushort4 v2 = *(const ushort4*)&Y[(size_t)p2.x * D + c];
    ushort4 v3 = *(const ushort4*)&Y[(size_t)p3.x * D + c];
    float w0 = __int_as_float(p0.y), w1 = __int_as_float(p1.y);
    float w2 = __int_as_float(p2.y), w3 = __int_as_float(p3.y);
    ax += w0 * bf2f(v0.x) + w1 * bf2f(v1.x) + w2 * bf2f(v2.x) + w3 * bf2f(v3.x);
    ay += w0 * bf2f(v0.y) + w1 * bf2f(v1.y) + w2 * bf2f(v2.y) + w3 * bf2f(v3.y);
    az += w0 * bf2f(v0.z) + w1 * bf2f(v1.z) + w2 * bf2f(v2.z) + w3 * bf2f(v3.z);
    aw += w0 * bf2f(v0.w) + w1 * bf2f(v1.w) + w2 * bf2f(v2.w) + w3 * bf2f(v3.w);
  }
  for (; j < len; j++) {
    int2 p = eeA[st + j];
    float w = __int_as_float(p.y);
    ushort4 v = *(const ushort4*)&Y[(size_t)p.x * D + c];
    ax += w * bf2f(v.x);
    ay += w * bf2f(v.y);
    az += w * bf2f(v.z);
    aw += w * bf2f(v.w);
  }
  float dv = dinvA[base];
  float d2 = dv * dv;
  ushort4 h = *(const ushort4*)&Y[(size_t)wid * D + c];
  ax += d2 * bf2f(h.x) + bias[c];
  ay += d2 * bf2f(h.y) + bias[c + 1];
  az += d2 * bf2f(h.z) + bias[c + 2];
  aw += d2 * bf2f(h.w) + bias[c + 3];
  ax = ax > 0.f ? ax : pa[c] * ax;
  ay = ay > 0.f ? ay : pa[c + 1] * ay;
  az = az > 0.f ? az : pa[c + 2] * az;
  aw = aw > 0.f ? aw : pa[c + 3] * aw;
  float* outT = out + (size_t)t * NN * D;
  *(float4*)&outT[(size_t)wid * D + c] = make_float4(ax, ay, az, aw);
}

// ---------------- launch ----------------

extern "C" void kernel_launch(void* const* d_in, const int* in_sizes, int n_in,
                              void* d_out, int out_size, void* d_ws, size_t ws_size,
                              hipStream_t stream) {
  const float* x = (const float*)d_in[0];
  const int* ei = (const int*)d_in[1];       // [4][2][NE] int32
  const float* ew = (const float*)d_in[2];   // [4][NE]
  const float* W0 = (const float*)d_in[3];
  const float* b0 = (const float*)d_in[4];
  const float* W1 = (const float*)d_in[5];
  const float* b1 = (const float*)d_in[6];
  const float* pa = (const float*)d_in[7];
  float* out = (float*)d_out;                // [4][NN][D] fp32

  // ws layout. Aliasing (sequential stream makes this safe):
  //   pack8 (8*NT ull = 12.8 MB) aliases H0h (NN*D bf16 = 12.8 MB, same size):
  //     pack8 dead after unpack_scan_k; H0h written by gemm_plain afterwards.
  //   cbase8 (8*NT u16 = 3.2 MB) aliases head of ZhA (51.2 MB):
  //     cbase8 dead after fill_all_k; ZhA written by gather1 afterwards.
  int2* eeA = (int2*)d_ws;                                // NS*NE int2  (25.6 MB)
  int* posA = (int*)(eeA + (size_t)NS * NE);              // NS*NE int   (12.8 MB)
  float* dinvA = (float*)(posA + (size_t)NS * NE);        // NT f32
  int* cntA = (int*)(dinvA + NT);                         // NT
  int* offsA = cntA + NT;                                 // NT
  int* partial = offsA + NT;                              // 1024
  int* poffs = partial + 1024;                            // 1024
  unsigned short* H0h = (unsigned short*)(poffs + 1024);  // NN*D bf16 (12.8 MB)
  unsigned short* ZhA = H0h + (size_t)NN * D;             // NS*NN*D bf16 (51.2 MB)
  unsigned short* Wsw = ZhA + (size_t)NS * NN * D;        // 32768 ushorts (64 KB)
  ull* pack8 = (ull*)H0h;                                 // alias
  unsigned short* cbase8 = ZhA;                           // alias

  const int gGemm = (NN + 63) / 64;           // 782
  const int gEdge = (NE + 255) / 256;         // 3125
  const int gEdge4 = (NE + 1023) / 1024;      // 782
  const int gInit8 = (8 * NT) / 256;          // 6250
  const int gGather = (NN * 32 + 255) / 256;  // 6250

  // batched CSR build for all 4 scales (8-way privatized histogram)
  initp_k<<<gInit8, 256, 0, stream>>>(pack8, 8 * NT);
  countpos_all_k<<<dim3(gEdge4, NS), 256, 0, stream>>>(ei, ew, pack8, posA);
  unpack_scan_k<<<SB2, 256, 0, stream>>>(pack8, dinvA, cntA, cbase8, partial);
  scan_top_k<<<1, 256, 0, stream>>>(partial, poffs, SB2);
  scan_write_k<<<SB2, 256, 0, stream>>>(cntA, poffs, offsA);
  fill_all_k<<<dim3(gEdge, NS), 256, 0, stream>>>(ei, ew, dinvA, offsA, posA,
                                                  cbase8, eeA);

  // H0h = bf16(x @ W0) — after unpack_scan (pack8 storage reused)
  gemm_plain_bf16out<<<gGemm, 256, 0, stream>>>(x, W0, H0h, NN);
  prep_w1_k<<<64, 256, 0, stream>>>(W1, Wsw);

  // layer 1 (all scales): ZhA[t] = bf16(prelu(Agg_t(H0h) + b0))
  gather1_all_k<<<dim3(gGather, NS), 256, 0, stream>>>(H0h, offsA, cntA, eeA,
                                                       dinvA, b0, pa, ZhA);
  // layer 2, commuted: Y = Zh@W1 (in-place, MFMA), then out = prelu(Agg_t(Y)+b1)
  gemm_inplace_mfma_k<<<dim3(gGemm, NS), 256, 0, stream>>>(ZhA, Wsw);
  gather2_all_k<<<dim3(gGather, NS), 256, 0, stream>>>(ZhA, offsA, cntA, eeA,
                                                       dinvA, b1, pa, out);
}

// Round 7
// 700.273 us; speedup vs baseline: 1.0404x; 1.0404x over previous
//
#include <hip/hip_runtime.h>

#define NN 50000
#define NE 800000
#define NS 4
#define NT (NS * NN)          // 200000
#define D 128
#define SB2 782               // ceil(NT/256)
#define EW_SCALE 262144.0f    // 2^18 fixed-point for packed degree
#define EW_INV (1.0f / 262144.0f)

typedef unsigned long long ull;
typedef __attribute__((ext_vector_type(8))) short bf16x8;
typedef __attribute__((ext_vector_type(4))) float f32x4;

__device__ __forceinline__ unsigned short f2bf(float f) {
  unsigned int u = __float_as_uint(f);
  u += 0x7fffu + ((u >> 16) & 1u);  // RNE
  return (unsigned short)(u >> 16);
}
__device__ __forceinline__ float bf2f(unsigned short h) {
  return __uint_as_float((unsigned int)h << 16);
}

// ---------------- fused: countpos (all scales) || x@W0 GEMM || W1 prep --------
// countpos is a hard atomic-throughput ceiling (~21.6 G RMW/s, wave- and
// pattern-insensitive: r5 1->4 atomics/lane = 0 delta, r6 8-way privatization
// = 0 delta) with VALUBusy 0.8% / HBM 10% — i.e. a 148 us idle window. The
// independent GEMM (x@W0 -> H0h bf16) + prep_w1 ride inside it for free.
// Grid (1628, NS): bx<782 countpos(bx,t); t==0 && bx<1564 gemm(bx-782);
// t==0 && bx>=1564 prep(bx-1564). LDS 49.3 KB -> 3 blocks/CU; atomic queue
// saturates at <=1536 in-flight lane-ops so 12 waves/CU still cap it.
__global__ __launch_bounds__(256) void fused_cpg_k(
    const int* __restrict__ ei, const float* __restrict__ ewA,
    ull* __restrict__ pack8, int* __restrict__ posA,
    const float* __restrict__ X, const float* __restrict__ W0,
    unsigned short* __restrict__ H0h,
    const float* __restrict__ W1, unsigned short* __restrict__ Wsw) {
  __shared__ float xs[64 * 130];
  __shared__ float ws[32 * 128];
  const int bx = blockIdx.x;
  const int t = blockIdx.y;
  const int tid = threadIdx.x;

  if (bx < 782) {
    // ---- countpos: 4 edges/thread, 8-way privatized histogram ----
    const int e0 = bx * 1024 + tid;
    const size_t cOff = (size_t)(bx & 7) * NT;
    const int* dst = ei + (size_t)t * 2 * NE + NE;
    const float* ew = ewA + (size_t)t * NE;
    int d[4];
    float w[4];
    bool va[4];
#pragma unroll
    for (int q = 0; q < 4; q++) {
      int e = e0 + q * 256;
      va[q] = e < NE;
      d[q] = 0;
      w[q] = 0.f;
      if (va[q]) {
        d[q] = dst[e];
        w[q] = ew[e];
      }
    }
    ull old[4];
#pragma unroll
    for (int q = 0; q < 4; q++) {
      if (va[q]) {
        ull add = (1ULL << 32) | (ull)__float2uint_rn(w[q] * EW_SCALE);
        old[q] = atomicAdd(&pack8[cOff + t * NN + d[q]], add);
      }
    }
#pragma unroll
    for (int q = 0; q < 4; q++) {
      if (va[q]) posA[(size_t)t * NE + e0 + q * 256] = (int)(old[q] >> 32);
    }
    return;
  }
  if (t != 0) return;

  if (bx < 1564) {
    // ---- gemm_plain: H0h = bf16(X @ W0), 64-row tile ----
    const int r0 = (bx - 782) * 64;
    for (int i = tid; i < 64 * 64; i += 256) {
      int row = i >> 6, kh = i & 63;
      float2 v = make_float2(0.f, 0.f);
      int gr = r0 + row;
      if (gr < NN) v = *(const float2*)&X[(size_t)gr * D + kh * 2];
      *(float2*)&xs[row * 130 + kh * 2] = v;
    }
    const int tx = tid & 15, ty = tid >> 4;
    const int c0 = tx * 4;
    const int c1 = 64 + tx * 4;
    float acc[4][8];
#pragma unroll
    for (int i = 0; i < 4; i++)
#pragma unroll
      for (int j = 0; j < 8; j++) acc[i][j] = 0.f;

    for (int kc = 0; kc < 4; kc++) {
      __syncthreads();
      for (int i = tid; i < 32 * 32; i += 256) {
        ((float4*)ws)[i] = ((const float4*)(W0 + kc * 32 * D))[i];
      }
      __syncthreads();
#pragma unroll 4
      for (int k2 = 0; k2 < 32; k2++) {
        const int k = kc * 32 + k2;
        float a[4];
#pragma unroll
        for (int j = 0; j < 4; j++) a[j] = xs[(ty * 4 + j) * 130 + k];
        float4 b0 = *(const float4*)&ws[k2 * 128 + c0];
        float4 b1 = *(const float4*)&ws[k2 * 128 + c1];
        float b[8] = {b0.x, b0.y, b0.z, b0.w, b1.x, b1.y, b1.z, b1.w};
#pragma unroll
        for (int i = 0; i < 4; i++)
#pragma unroll
          for (int j = 0; j < 8; j++) acc[i][j] += a[i] * b[j];
      }
    }
#pragma unroll
    for (int i = 0; i < 4; i++) {
      int gr = r0 + ty * 4 + i;
      if (gr < NN) {
        ushort4 o0, o1;
        o0.x = f2bf(acc[i][0]); o0.y = f2bf(acc[i][1]);
        o0.z = f2bf(acc[i][2]); o0.w = f2bf(acc[i][3]);
        o1.x = f2bf(acc[i][4]); o1.y = f2bf(acc[i][5]);
        o1.z = f2bf(acc[i][6]); o1.w = f2bf(acc[i][7]);
        *(ushort4*)&H0h[(size_t)gr * D + c0] = o0;
        *(ushort4*)&H0h[(size_t)gr * D + c1] = o1;
      }
    }
  } else {
    // ---- prep_w1: hi/lo bf16 split of W1 into MFMA lane order ----
    int idx = (bx - 1564) * 256 + tid;  // 16384 total
    int j = idx & 7, lane = (idx >> 3) & 63, s = (idx >> 9) & 3, bn = idx >> 11;
    float v = W1[(s * 32 + ((lane >> 4) * 8) + j) * D + bn * 16 + (lane & 15)];
    unsigned short hi = f2bf(v);
    float lo = v - bf2f(hi);
    Wsw[idx] = hi;
    Wsw[16384 + idx] = f2bf(lo);
  }
}

// ---------------- in-place MFMA GEMM: Zh[t] <- bf16(Zh[t] @ W1) ----------------
__global__ __launch_bounds__(256) void gemm_inplace_mfma_k(
    unsigned short* __restrict__ ZhA, const unsigned short* __restrict__ Wsw) {
  const int t = blockIdx.y;
  unsigned short* Z = ZhA + (size_t)t * NN * D;
  const int tid = threadIdx.x;
  const int wv = tid >> 6, l = tid & 63;
  const int r0 = blockIdx.x * 64 + wv * 16;
  const int mrow = r0 + (l & 15);
  const int arow = mrow < NN ? mrow : NN - 1;
  bf16x8 a[4];
#pragma unroll
  for (int s = 0; s < 4; s++)
    a[s] = *(const bf16x8*)&Z[(size_t)arow * D + s * 32 + (l >> 4) * 8];
  const int orow0 = r0 + (l >> 4) * 4;
#pragma unroll
  for (int bn = 0; bn < 8; bn++) {
    f32x4 acc = {0.f, 0.f, 0.f, 0.f};
#pragma unroll
    for (int s = 0; s < 4; s++) {
      bf16x8 blo = *(const bf16x8*)&Wsw[16384 + ((bn * 4 + s) * 64 + l) * 8];
      bf16x8 bhi = *(const bf16x8*)&Wsw[((bn * 4 + s) * 64 + l) * 8];
      acc = __builtin_amdgcn_mfma_f32_16x16x32_bf16(a[s], blo, acc, 0, 0, 0);
      acc = __builtin_amdgcn_mfma_f32_16x16x32_bf16(a[s], bhi, acc, 0, 0, 0);
    }
    const int col = bn * 16 + (l & 15);
#pragma unroll
    for (int i = 0; i < 4; i++) {
      int row = orow0 + i;
      if (row < NN) Z[(size_t)row * D + col] = f2bf(acc[i]);
    }
  }
}

// ---------------- CSR build, batched over all 4 scales ----------------

__global__ __launch_bounds__(256) void initp_k(ull* __restrict__ packed, int n) {
  int i = blockIdx.x * 256 + threadIdx.x;
  if (i < n) packed[i] = 0ULL;
}

// unpack 8 copies + per-copy exclusive base + per-block partial sum. grid SB2.
__global__ __launch_bounds__(256) void unpack_scan_k(const ull* __restrict__ pack8,
                                                     float* __restrict__ dinvA,
                                                     int* __restrict__ cntA,
                                                     unsigned short* __restrict__ cbase8,
                                                     int* __restrict__ partial) {
  __shared__ int sm[256];
  const int tid = threadIdx.x;
  const int i = blockIdx.x * 256 + tid;
  int c = 0;
  if (i < NT) {
    unsigned int wsum = 0;
    int run = 0;
#pragma unroll
    for (int k = 0; k < 8; k++) {
      ull p = pack8[(size_t)k * NT + i];
      cbase8[(size_t)k * NT + i] = (unsigned short)run;
      run += (int)(p >> 32);
      wsum += (unsigned int)(p & 0xffffffffULL);
    }
    c = run;
    cntA[i] = c;
    float deg = 1.0f + (float)wsum * EW_INV;
    dinvA[i] = rsqrtf(deg);
  }
  sm[tid] = c;
  __syncthreads();
  for (int off = 128; off > 0; off >>= 1) {
    if (tid < off) sm[tid] += sm[tid + off];
    __syncthreads();
  }
  if (tid == 0) partial[blockIdx.x] = sm[0];
}

// scan_write with integrated top-level scan: each block sums partial[0..bx)
// itself (3 KB, L2-hot) — removes the scan_top kernel + poffs round trip.
__global__ __launch_bounds__(256) void scan_write_k(const int* __restrict__ cntA,
                                                    const int* __restrict__ partial,
                                                    int* __restrict__ offsA) {
  __shared__ int sm[256];
  const int t = threadIdx.x;
  const int bx = blockIdx.x;
  int s = 0;
  for (int i = t; i < bx; i += 256) s += partial[i];
  sm[t] = s;
  __syncthreads();
  for (int off = 128; off > 0; off >>= 1) {
    if (t < off) sm[t] += sm[t + off];
    __syncthreads();
  }
  const int base = sm[0];
  __syncthreads();
  const int i = bx * 256 + t;
  int v = (i < NT) ? cntA[i] : 0;
  sm[t] = v;
  __syncthreads();
  for (int off = 1; off < 256; off <<= 1) {
    int u = (t >= off) ? sm[t - off] : 0;
    __syncthreads();
    sm[t] += u;
    __syncthreads();
  }
  if (i < NT) offsA[i] = base + sm[t] - v;
}

// grid (3125, NS): slot = offs[d] + cbase8[copy][d] + pos, copy = (e>>10)&7.
__global__ __launch_bounds__(256) void fill_all_k(const int* __restrict__ ei,
                                                  const float* __restrict__ ewA,
                                                  const float* __restrict__ dinvA,
                                                  const int* __restrict__ offsA,
                                                  const int* __restrict__ posA,
                                                  const unsigned short* __restrict__ cbase8,
                                                  int2* __restrict__ eeA) {
  const int t = blockIdx.y;
  const int e = blockIdx.x * 256 + threadIdx.x;
  if (e < NE) {
    const int* src = ei + (size_t)t * 2 * NE;
    const int* dst = src + NE;
    int s = src[e], d = dst[e];
    const int base = t * NN + d;
    const size_t cOff = (size_t)((e >> 10) & 7) * NT;
    float w = ewA[(size_t)t * NE + e] * dinvA[t * NN + s] * dinvA[base];
    int slot = offsA[base] + (int)cbase8[cOff + base] + posA[(size_t)t * NE + e];
    eeA[slot] = make_int2(s, __float_as_int(w));
  }
}

// ---------------- layer-1 gather, batched: grid (6250, NS) ----------------
__global__ __launch_bounds__(256) void gather1_all_k(
    const unsigned short* __restrict__ H, const int* __restrict__ offsA,
    const int* __restrict__ cntA, const int2* __restrict__ eeA,
    const float* __restrict__ dinvA, const float* __restrict__ bias,
    const float* __restrict__ pa, unsigned short* __restrict__ ZhA) {
  const int t = blockIdx.y;
  int g = blockIdx.x * 256 + threadIdx.x;
  int wid = g >> 5;
  int lane = g & 31;
  if (wid >= NN) return;
  const int base = t * NN + wid;
  const int st = offsA[base];
  const int len = cntA[base];
  const int c = lane * 4;
  float ax = 0.f, ay = 0.f, az = 0.f, aw = 0.f;
  int j = 0;
  for (; j + 8 <= len; j += 8) {
    int2 p0 = eeA[st + j];
    int2 p1 = eeA[st + j + 1];
    int2 p2 = eeA[st + j + 2];
    int2 p3 = eeA[st + j + 3];
    int2 p4 = eeA[st + j + 4];
    int2 p5 = eeA[st + j + 5];
    int2 p6 = eeA[st + j + 6];
    int2 p7 = eeA[st + j + 7];
    ushort4 v0 = *(const ushort4*)&H[(size_t)p0.x * D + c];
    ushort4 v1 = *(const ushort4*)&H[(size_t)p1.x * D + c];
    ushort4 v2 = *(const ushort4*)&H[(size_t)p2.x * D + c];
    ushort4 v3 = *(const ushort4*)&H[(size_t)p3.x * D + c];
    ushort4 v4 = *(const ushort4*)&H[(size_t)p4.x * D + c];
    ushort4 v5 = *(const ushort4*)&H[(size_t)p5.x * D + c];
    ushort4 v6 = *(const ushort4*)&H[(size_t)p6.x * D + c];
    ushort4 v7 = *(const ushort4*)&H[(size_t)p7.x * D + c];
    float w0 = __int_as_float(p0.y), w1 = __int_as_float(p1.y);
    float w2 = __int_as_float(p2.y), w3 = __int_as_float(p3.y);
    float w4 = __int_as_float(p4.y), w5 = __int_as_float(p5.y);
    float w6 = __int_as_float(p6.y), w7 = __int_as_float(p7.y);
    ax += w0 * bf2f(v0.x) + w1 * bf2f(v1.x) + w2 * bf2f(v2.x) + w3 * bf2f(v3.x);
    ay += w0 * bf2f(v0.y) + w1 * bf2f(v1.y) + w2 * bf2f(v2.y) + w3 * bf2f(v3.y);
    az += w0 * bf2f(v0.z) + w1 * bf2f(v1.z) + w2 * bf2f(v2.z) + w3 * bf2f(v3.z);
    aw += w0 * bf2f(v0.w) + w1 * bf2f(v1.w) + w2 * bf2f(v2.w) + w3 * bf2f(v3.w);
    ax += w4 * bf2f(v4.x) + w5 * bf2f(v5.x) + w6 * bf2f(v6.x) + w7 * bf2f(v7.x);
    ay += w4 * bf2f(v4.y) + w5 * bf2f(v5.y) + w6 * bf2f(v6.y) + w7 * bf2f(v7.y);
    az += w4 * bf2f(v4.z) + w5 * bf2f(v5.z) + w6 * bf2f(v6.z) + w7 * bf2f(v7.z);
    aw += w4 * bf2f(v4.w) + w5 * bf2f(v5.w) + w6 * bf2f(v6.w) + w7 * bf2f(v7.w);
  }
  for (; j + 4 <= len; j += 4) {
    int2 p0 = eeA[st + j];
    int2 p1 = eeA[st + j + 1];
    int2 p2 = eeA[st + j + 2];
    int2 p3 = eeA[st + j + 3];
    ushort4 v0 = *(const ushort4*)&H[(size_t)p0.x * D + c];
    ushort4 v1 = *(const ushort4*)&H[(size_t)p1.x * D + c];
    ushort4 v2 = *(const ushort4*)&H[(size_t)p2.x * D + c];
    ushort4 v3 = *(const ushort4*)&H[(size_t)p3.x * D + c];
    float w0 = __int_as_float(p0.y), w1 = __int_as_float(p1.y);
    float w2 = __int_as_float(p2.y), w3 = __int_as_float(p3.y);
    ax += w0 * bf2f(v0.x) + w1 * bf2f(v1.x) + w2 * bf2f(v2.x) + w3 * bf2f(v3.x);
    ay += w0 * bf2f(v0.y) + w1 * bf2f(v1.y) + w2 * bf2f(v2.y) + w3 * bf2f(v3.y);
    az += w0 * bf2f(v0.z) + w1 * bf2f(v1.z) + w2 * bf2f(v2.z) + w3 * bf2f(v3.z);
    aw += w0 * bf2f(v0.w) + w1 * bf2f(v1.w) + w2 * bf2f(v2.w) + w3 * bf2f(v3.w);
  }
  for (; j < len; j++) {
    int2 p = eeA[st + j];
    float w = __int_as_float(p.y);
    ushort4 v = *(const ushort4*)&H[(size_t)p.x * D + c];
    ax += w * bf2f(v.x);
    ay += w * bf2f(v.y);
    az += w * bf2f(v.z);
    aw += w * bf2f(v.w);
  }
  float dv = dinvA[base];
  float d2 = dv * dv;
  ushort4 h = *(const ushort4*)&H[(size_t)wid * D + c];
  ax += d2 * bf2f(h.x) + bias[c];
  ay += d2 * bf2f(h.y) + bias[c + 1];
  az += d2 * bf2f(h.z) + bias[c + 2];
  aw += d2 * bf2f(h.w) + bias[c + 3];
  ax = ax > 0.f ? ax : pa[c] * ax;
  ay = ay > 0.f ? ay : pa[c + 1] * ay;
  az = az > 0.f ? az : pa[c + 2] * az;
  aw = aw > 0.f ? aw : pa[c + 3] * aw;
  ushort4 o;
  o.x = f2bf(ax); o.y = f2bf(ay); o.z = f2bf(az); o.w = f2bf(aw);
  *(ushort4*)&ZhA[(size_t)t * NN * D + (size_t)wid * D + c] = o;
}

// ---------------- layer-2 gather, batched: grid (6250, NS) ----------------
__global__ __launch_bounds__(256) void gather2_all_k(
    const unsigned short* __restrict__ YA, const int* __restrict__ offsA,
    const int* __restrict__ cntA, const int2* __restrict__ eeA,
    const float* __restrict__ dinvA, const float* __restrict__ bias,
    const float* __restrict__ pa, float* __restrict__ out) {
  const int t = blockIdx.y;
  int g = blockIdx.x * 256 + threadIdx.x;
  int wid = g >> 5;
  int lane = g & 31;
  if (wid >= NN) return;
  const unsigned short* Y = YA + (size_t)t * NN * D;
  const int base = t * NN + wid;
  const int st = offsA[base];
  const int len = cntA[base];
  const int c = lane * 4;
  float ax = 0.f, ay = 0.f, az = 0.f, aw = 0.f;
  int j = 0;
  for (; j + 8 <= len; j += 8) {
    int2 p0 = eeA[st + j];
    int2 p1 = eeA[st + j + 1];
    int2 p2 = eeA[st + j + 2];
    int2 p3 = eeA[st + j + 3];
    int2 p4 = eeA[st + j + 4];
    int2 p5 = eeA[st + j + 5];
    int2 p6 = eeA[st + j + 6];
    int2 p7 = eeA[st + j + 7];
    ushort4 v0 = *(const ushort4*)&Y[(size_t)p0.x * D + c];
    ushort4 v1 = *(const ushort4*)&Y[(size_t)p1.x * D + c];
    ushort4 v2 = *(const ushort4*)&Y[(size_t)p2.x * D + c];
    ushort4 v3 = *(const ushort4*)&Y[(size_t)p3.x * D + c];
    ushort4 v4 = *(const ushort4*)&Y[(size_t)p4.x * D + c];
    ushort4 v5 = *(const ushort4*)&Y[(size_t)p5.x * D + c];
    ushort4 v6 = *(const ushort4*)&Y[(size_t)p6.x * D + c];
    ushort4 v7 = *(const ushort4*)&Y[(size_t)p7.x * D + c];
    float w0 = __int_as_float(p0.y), w1 = __int_as_float(p1.y);
    float w2 = __int_as_float(p2.y), w3 = __int_as_float(p3.y);
    float w4 = __int_as_float(p4.y), w5 = __int_as_float(p5.y);
    float w6 = __int_as_float(p6.y), w7 = __int_as_float(p7.y);
    ax += w0 * bf2f(v0.x) + w1 * bf2f(v1.x) + w2 * bf2f(v2.x) + w3 * bf2f(v3.x);
    ay += w0 * bf2f(v0.y) + w1 * bf2f(v1.y) + w2 * bf2f(v2.y) + w3 * bf2f(v3.y);
    az += w0 * bf2f(v0.z) + w1 * bf2f(v1.z) + w2 * bf2f(v2.z) + w3 * bf2f(v3.z);
    aw += w0 * bf2f(v0.w) + w1 * bf2f(v1.w) + w2 * bf2f(v2.w) + w3 * bf2f(v3.w);
    ax += w4 * bf2f(v4.x) + w5 * bf2f(v5.x) + w6 * bf2f(v6.x) + w7 * bf2f(v7.x);
    ay += w4 * bf2f(v4.y) + w5 * bf2f(v5.y) + w6 * bf2f(v6.y) + w7 * bf2f(v7.y);
    az += w4 * bf2f(v4.z) + w5 * bf2f(v5.z) + w6 * bf2f(v6.z) + w7 * bf2f(v7.z);
    aw += w4 * bf2f(v4.w) + w5 * bf2f(v5.w) + w6 * bf2f(v6.w) + w7 * bf2f(v7.w);
  }
  for (; j + 4 <= len; j += 4) {
    int2 p0 = eeA[st + j];
    int2 p1 = eeA[st + j + 1];
    int2 p2 = eeA[st + j + 2];
    int2 p3 = eeA[st + j + 3];
    ushort4 v0 = *(const ushort4*)&Y[(size_t)p0.x * D + c];
    ushort4 v1 = *(const ushort4*)&Y[(size_t)p1.x * D + c];
    ushort4 v2 = *(const ushort4*)&Y[(size_t)p2.x * D + c];
    ushort4 v3 = *(const ushort4*)&Y[(size_t)p3.x * D + c];
    float w0 = __int_as_float(p0.y), w1 = __int_as_float(p1.y);
    float w2 = __int_as_float(p2.y), w3 = __int_as_float(p3.y);
    ax += w0 * bf2f(v0.x) + w1 * bf2f(v1.x) + w2 * bf2f(v2.x) + w3 * bf2f(v3.x);
    ay += w0 * bf2f(v0.y) + w1 * bf2f(v1.y) + w2 * bf2f(v2.y) + w3 * bf2f(v3.y);
    az += w0 * bf2f(v0.z) + w1 * bf2f(v1.z) + w2 * bf2f(v2.z) + w3 * bf2f(v3.z);
    aw += w0 * bf2f(v0.w) + w1 * bf2f(v1.w) + w2 * bf2f(v2.w) + w3 * bf2f(v3.w);
  }
  for (; j < len; j++) {
    int2 p = eeA[st + j];
    float w = __int_as_float(p.y);
    ushort4 v = *(const ushort4*)&Y[(size_t)p.x * D + c];
    ax += w * bf2f(v.x);
    ay += w * bf2f(v.y);
    az += w * bf2f(v.z);
    aw += w * bf2f(v.w);
  }
  float dv = dinvA[base];
  float d2 = dv * dv;
  ushort4 h = *(const ushort4*)&Y[(size_t)wid * D + c];
  ax += d2 * bf2f(h.x) + bias[c];
  ay += d2 * bf2f(h.y) + bias[c + 1];
  az += d2 * bf2f(h.z) + bias[c + 2];
  aw += d2 * bf2f(h.w) + bias[c + 3];
  ax = ax > 0.f ? ax : pa[c] * ax;
  ay = ay > 0.f ? ay : pa[c + 1] * ay;
  az = az > 0.f ? az : pa[c + 2] * az;
  aw = aw > 0.f ? aw : pa[c + 3] * aw;
  float* outT = out + (size_t)t * NN * D;
  *(float4*)&outT[(size_t)wid * D + c] = make_float4(ax, ay, az, aw);
}

// ---------------- launch ----------------

extern "C" void kernel_launch(void* const* d_in, const int* in_sizes, int n_in,
                              void* d_out, int out_size, void* d_ws, size_t ws_size,
                              hipStream_t stream) {
  const float* x = (const float*)d_in[0];
  const int* ei = (const int*)d_in[1];       // [4][2][NE] int32
  const float* ew = (const float*)d_in[2];   // [4][NE]
  const float* W0 = (const float*)d_in[3];
  const float* b0 = (const float*)d_in[4];
  const float* W1 = (const float*)d_in[5];
  const float* b1 = (const float*)d_in[6];
  const float* pa = (const float*)d_in[7];
  float* out = (float*)d_out;                // [4][NN][D] fp32

  // ws layout. Aliasing: cbase8 (3.2 MB) + pack8 (12.8 MB) live in the FIRST
  // 16 MB of ZhA (51.2 MB). Both are dead after fill_all_k; gather1 writes all
  // of ZhA afterwards. H0h is NOT aliased (gemm writes it concurrently with
  // countpos atomics inside fused_cpg_k).
  int2* eeA = (int2*)d_ws;                                // NS*NE int2  (25.6 MB)
  int* posA = (int*)(eeA + (size_t)NS * NE);              // NS*NE int   (12.8 MB)
  float* dinvA = (float*)(posA + (size_t)NS * NE);        // NT f32
  int* cntA = (int*)(dinvA + NT);                         // NT
  int* offsA = cntA + NT;                                 // NT
  int* partial = offsA + NT;                              // 1024
  int* poffs = partial + 1024;                            // 1024 (unused, layout keep)
  unsigned short* H0h = (unsigned short*)(poffs + 1024);  // NN*D bf16 (12.8 MB)
  unsigned short* ZhA = H0h + (size_t)NN * D;             // NS*NN*D bf16 (51.2 MB)
  unsigned short* Wsw = ZhA + (size_t)NS * NN * D;        // 32768 ushorts (64 KB)
  unsigned short* cbase8 = ZhA;                           // alias: 8*NT u16
  ull* pack8 = (ull*)(ZhA + (size_t)8 * NT);              // alias: 8*NT ull

  const int gGemm = (NN + 63) / 64;           // 782
  const int gEdge = (NE + 255) / 256;         // 3125
  const int gInit8 = (8 * NT) / 256;          // 6250
  const int gGather = (NN * 32 + 255) / 256;  // 6250
  const int gFused = 782 + 782 + 64;          // countpos + gemm + prep

  // init histogram, then fused {countpos || x@W0 gemm || W1 prep}
  initp_k<<<gInit8, 256, 0, stream>>>(pack8, 8 * NT);
  fused_cpg_k<<<dim3(gFused, NS), 256, 0, stream>>>(ei, ew, pack8, posA,
                                                    x, W0, H0h, W1, Wsw);

  unpack_scan_k<<<SB2, 256, 0, stream>>>(pack8, dinvA, cntA, cbase8, partial);
  scan_write_k<<<SB2, 256, 0, stream>>>(cntA, partial, offsA);
  fill_all_k<<<dim3(gEdge, NS), 256, 0, stream>>>(ei, ew, dinvA, offsA, posA,
                                                  cbase8, eeA);

  // layer 1 (all scales): ZhA[t] = bf16(prelu(Agg_t(H0h) + b0))
  gather1_all_k<<<dim3(gGather, NS), 256, 0, stream>>>(H0h, offsA, cntA, eeA,
                                                       dinvA, b0, pa, ZhA);
  // layer 2, commuted: Y = Zh@W1 (in-place, MFMA), then out = prelu(Agg_t(Y)+b1)
  gemm_inplace_mfma_k<<<dim3(gGemm, NS), 256, 0, stream>>>(ZhA, Wsw);
  gather2_all_k<<<dim3(gGather, NS), 256, 0, stream>>>(ZhA, offsA, cntA, eeA,
                                                       dinvA, b1, pa, out);
}

// Round 8
// 595.229 us; speedup vs baseline: 1.2240x; 1.1765x over previous
//
#include <hip/hip_runtime.h>

#define NN 50000
#define NE 800000
#define NS 4
#define NT (NS * NN)          // 200000
#define D 128
#define NB 196                // bins of 256 dst: ceil(NN/256)
#define CB 782                // edge chunks: ceil(NE/1024)
#define EW_SCALE 262144.0f    // 2^18 fixed-point for degree accumulation
#define EW_INV (1.0f / 262144.0f)

typedef unsigned int u32;
typedef unsigned long long ull;
typedef __attribute__((ext_vector_type(8))) short bf16x8;
typedef __attribute__((ext_vector_type(4))) float f32x4;

__device__ __forceinline__ unsigned short f2bf(float f) {
  unsigned int u = __float_as_uint(f);
  u += 0x7fffu + ((u >> 16) & 1u);  // RNE
  return (unsigned short)(u >> 16);
}
__device__ __forceinline__ float bf2f(unsigned short h) {
  return __uint_as_float((unsigned int)h << 16);
}

// ---- fused: per-block bin histogram (all scales) || x@W0 GEMM || W1 prep ----
// No global atomics anywhere in the new CSR build: r4-r7 established that
// device-scope RMWs run memory-side (WRITE_SIZE ~ 35 B/atomic) at a hard
// ~21.6 G/s ceiling. Counting sort with LDS atomics replaces them.
// Grid (782+782+64, NS): bx<782 hist(bx,t); t==0: bx<1564 gemm, else prep.
__global__ __launch_bounds__(256) void fused_hg_k(
    const int* __restrict__ ei, u32* __restrict__ ghist,
    const float* __restrict__ X, const float* __restrict__ W0,
    unsigned short* __restrict__ H0h,
    const float* __restrict__ W1, unsigned short* __restrict__ Wsw) {
  __shared__ float xs[64 * 130];
  __shared__ float ws[32 * 128];
  __shared__ u32 h[NB];
  const int bx = blockIdx.x;
  const int t = blockIdx.y;
  const int tid = threadIdx.x;

  if (bx < CB) {
    // ---- histogram of dst>>8 over this block's 1024 edges ----
    if (tid < NB) h[tid] = 0;
    __syncthreads();
    const int* dst = ei + (size_t)t * 2 * NE + NE;
#pragma unroll
    for (int q = 0; q < 4; q++) {
      int e = bx * 1024 + q * 256 + tid;
      if (e < NE) atomicAdd(&h[(u32)dst[e] >> 8], 1u);
    }
    __syncthreads();
    if (tid < NB) ghist[((size_t)t * NB + tid) * CB + bx] = h[tid];
    return;
  }
  if (t != 0) return;

  if (bx < 2 * CB) {
    // ---- gemm_plain: H0h = bf16(X @ W0), 64-row tile ----
    const int r0 = (bx - CB) * 64;
    for (int i = tid; i < 64 * 64; i += 256) {
      int row = i >> 6, kh = i & 63;
      float2 v = make_float2(0.f, 0.f);
      int gr = r0 + row;
      if (gr < NN) v = *(const float2*)&X[(size_t)gr * D + kh * 2];
      *(float2*)&xs[row * 130 + kh * 2] = v;
    }
    const int tx = tid & 15, ty = tid >> 4;
    const int c0 = tx * 4;
    const int c1 = 64 + tx * 4;
    float acc[4][8];
#pragma unroll
    for (int i = 0; i < 4; i++)
#pragma unroll
      for (int j = 0; j < 8; j++) acc[i][j] = 0.f;

    for (int kc = 0; kc < 4; kc++) {
      __syncthreads();
      for (int i = tid; i < 32 * 32; i += 256) {
        ((float4*)ws)[i] = ((const float4*)(W0 + kc * 32 * D))[i];
      }
      __syncthreads();
#pragma unroll 4
      for (int k2 = 0; k2 < 32; k2++) {
        const int k = kc * 32 + k2;
        float a[4];
#pragma unroll
        for (int j = 0; j < 4; j++) a[j] = xs[(ty * 4 + j) * 130 + k];
        float4 b0 = *(const float4*)&ws[k2 * 128 + c0];
        float4 b1 = *(const float4*)&ws[k2 * 128 + c1];
        float b[8] = {b0.x, b0.y, b0.z, b0.w, b1.x, b1.y, b1.z, b1.w};
#pragma unroll
        for (int i = 0; i < 4; i++)
#pragma unroll
          for (int j = 0; j < 8; j++) acc[i][j] += a[i] * b[j];
      }
    }
#pragma unroll
    for (int i = 0; i < 4; i++) {
      int gr = r0 + ty * 4 + i;
      if (gr < NN) {
        ushort4 o0, o1;
        o0.x = f2bf(acc[i][0]); o0.y = f2bf(acc[i][1]);
        o0.z = f2bf(acc[i][2]); o0.w = f2bf(acc[i][3]);
        o1.x = f2bf(acc[i][4]); o1.y = f2bf(acc[i][5]);
        o1.z = f2bf(acc[i][6]); o1.w = f2bf(acc[i][7]);
        *(ushort4*)&H0h[(size_t)gr * D + c0] = o0;
        *(ushort4*)&H0h[(size_t)gr * D + c1] = o1;
      }
    }
  } else {
    // ---- prep_w1: hi/lo bf16 split of W1 into MFMA lane order ----
    int idx = (bx - 2 * CB) * 256 + tid;  // 16384 total
    int j = idx & 7, lane = (idx >> 3) & 63, s = (idx >> 9) & 3, bn = idx >> 11;
    float v = W1[(s * 32 + ((lane >> 4) * 8) + j) * D + bn * 16 + (lane & 15)];
    unsigned short hi = f2bf(v);
    float lo = v - bf2f(hi);
    Wsw[idx] = hi;
    Wsw[16384 + idx] = f2bf(lo);
  }
}

// ---- within-bin exclusive scan over the 782 chunk-blocks; total -> bincnt ----
// grid (NB, NS); ghist row [t][b][0..781] rewritten in place to exclusive.
__global__ __launch_bounds__(256) void scanbin_k(u32* __restrict__ ghist,
                                                 u32* __restrict__ bincnt) {
  __shared__ int sm[256];
  const int b = blockIdx.x, t = blockIdx.y, tid = threadIdx.x;
  u32* g = ghist + ((size_t)t * NB + b) * CB;
  const int lo = tid * 4;
  const int hi = min(lo + 4, CB);
  int s = 0;
  for (int i = lo; i < hi; i++) s += (int)g[i];
  sm[tid] = s;
  __syncthreads();
  for (int off = 1; off < 256; off <<= 1) {
    int u = (tid >= off) ? sm[tid - off] : 0;
    __syncthreads();
    sm[tid] += u;
    __syncthreads();
  }
  int run = sm[tid] - s;  // exclusive
  for (int i = lo; i < hi; i++) {
    u32 v = g[i];
    g[i] = (u32)run;
    run += (int)v;
  }
  if (lo < CB && hi == CB) bincnt[t * NB + b] = (u32)run;
}

// ---- exclusive scan of bincnt -> binbase. grid (1, NS). ----
__global__ __launch_bounds__(256) void binbase_k(const u32* __restrict__ bincnt,
                                                 u32* __restrict__ binbase) {
  __shared__ int sm[256];
  const int t = blockIdx.y, tid = threadIdx.x;
  int v = (tid < NB) ? (int)bincnt[t * NB + tid] : 0;
  sm[tid] = v;
  __syncthreads();
  for (int off = 1; off < 256; off <<= 1) {
    int u = (tid >= off) ? sm[tid - off] : 0;
    __syncthreads();
    sm[tid] += u;
    __syncthreads();
  }
  if (tid < NB) binbase[t * NB + tid] = (u32)(sm[tid] - v);
}

// ---- scatter edges into bin-contiguous order via LDS counters. grid (782,NS) --
// record: .x = (dst<<16)|src (both < 65536), .y = raw ew bits.
__global__ __launch_bounds__(256) void scat_k(const int* __restrict__ ei,
                                              const float* __restrict__ ewA,
                                              const u32* __restrict__ ghist,
                                              const u32* __restrict__ binbase,
                                              int2* __restrict__ ebin) {
  __shared__ u32 c[NB];
  __shared__ int bb[NB];
  const int bx = blockIdx.x, t = blockIdx.y, tid = threadIdx.x;
  if (tid < NB) {
    c[tid] = ghist[((size_t)t * NB + tid) * CB + bx];
    bb[tid] = (int)binbase[t * NB + tid];
  }
  __syncthreads();
  const int* src = ei + (size_t)t * 2 * NE;
  const int* dst = src + NE;
  const float* ew = ewA + (size_t)t * NE;
  int2* eb = ebin + (size_t)t * NE;
#pragma unroll
  for (int q = 0; q < 4; q++) {
    int e = bx * 1024 + q * 256 + tid;
    if (e < NE) {
      u32 d = (u32)dst[e];
      u32 s = (u32)src[e];
      float w = ew[e];
      u32 bin = d >> 8;
      u32 r = atomicAdd(&c[bin], 1u);
      eb[bb[bin] + r] = make_int2((int)((d << 16) | s), __float_as_int(w));
    }
  }
}

// ---- per-bin CSR finalize. grid (NB, NS). Counts, offsets, degree->dinv, and
// final within-bin scatter, all with LDS counters. ----
__global__ __launch_bounds__(256) void bincsr_k(const int2* __restrict__ ebin,
                                                const u32* __restrict__ bincnt,
                                                const u32* __restrict__ binbase,
                                                int* __restrict__ cntA,
                                                int* __restrict__ offsA,
                                                float* __restrict__ dinvA,
                                                int2* __restrict__ eeA) {
  __shared__ u32 cnt[256];
  __shared__ u32 wsum[256];
  __shared__ u32 c2[256];
  __shared__ int sm[256];
  __shared__ int excls[256];
  const int b = blockIdx.x, t = blockIdx.y, tid = threadIdx.x;
  const int m = (int)bincnt[t * NB + b];
  const int bb = (int)binbase[t * NB + b];
  const int2* eb = ebin + (size_t)t * NE + bb;
  cnt[tid] = 0;
  wsum[tid] = 0;
  c2[tid] = 0;
  __syncthreads();
  for (int i = tid; i < m; i += 256) {
    int2 r = eb[i];
    u32 dl = ((u32)r.x >> 16) & 255u;
    atomicAdd(&cnt[dl], 1u);
    atomicAdd(&wsum[dl], (u32)__float2uint_rn(__int_as_float(r.y) * EW_SCALE));
  }
  __syncthreads();
  int v = (int)cnt[tid];
  sm[tid] = v;
  __syncthreads();
  for (int off = 1; off < 256; off <<= 1) {
    int u = (tid >= off) ? sm[tid - off] : 0;
    __syncthreads();
    sm[tid] += u;
    __syncthreads();
  }
  const int excl = sm[tid] - v;
  excls[tid] = excl;
  const int g = b * 256 + tid;
  if (g < NN) {
    cntA[t * NN + g] = v;
    offsA[t * NN + g] = t * NE + bb + excl;
    float deg = 1.0f + (float)wsum[tid] * EW_INV;
    dinvA[t * NN + g] = rsqrtf(deg);
  }
  __syncthreads();
  int2* ee = eeA + (size_t)t * NE + bb;
  for (int i = tid; i < m; i += 256) {
    int2 r = eb[i];
    u32 dl = ((u32)r.x >> 16) & 255u;
    u32 rk = atomicAdd(&c2[dl], 1u);
    ee[excls[dl] + (int)rk] = r;  // still packed; rescale_k unpacks
  }
}

// ---- linear rescale: (packed, ew) -> (src, ew*dinv_s*dinv_d). grid (3125,NS) --
__global__ __launch_bounds__(256) void rescale_k(const float* __restrict__ dinvA,
                                                 int2* __restrict__ eeA) {
  const int t = blockIdx.y;
  const int e = blockIdx.x * 256 + threadIdx.x;
  if (e < NE) {
    int2 r = eeA[(size_t)t * NE + e];
    int s = r.x & 0xffff;
    int d = (int)((u32)r.x >> 16);
    const float* dv = dinvA + t * NN;
    float w = __int_as_float(r.y) * dv[s] * dv[d];
    eeA[(size_t)t * NE + e] = make_int2(s, __float_as_int(w));
  }
}

// ---------------- in-place MFMA GEMM: Zh[t] <- bf16(Zh[t] @ W1) ----------------
__global__ __launch_bounds__(256) void gemm_inplace_mfma_k(
    unsigned short* __restrict__ ZhA, const unsigned short* __restrict__ Wsw) {
  const int t = blockIdx.y;
  unsigned short* Z = ZhA + (size_t)t * NN * D;
  const int tid = threadIdx.x;
  const int wv = tid >> 6, l = tid & 63;
  const int r0 = blockIdx.x * 64 + wv * 16;
  const int mrow = r0 + (l & 15);
  const int arow = mrow < NN ? mrow : NN - 1;
  bf16x8 a[4];
#pragma unroll
  for (int s = 0; s < 4; s++)
    a[s] = *(const bf16x8*)&Z[(size_t)arow * D + s * 32 + (l >> 4) * 8];
  const int orow0 = r0 + (l >> 4) * 4;
#pragma unroll
  for (int bn = 0; bn < 8; bn++) {
    f32x4 acc = {0.f, 0.f, 0.f, 0.f};
#pragma unroll
    for (int s = 0; s < 4; s++) {
      bf16x8 blo = *(const bf16x8*)&Wsw[16384 + ((bn * 4 + s) * 64 + l) * 8];
      bf16x8 bhi = *(const bf16x8*)&Wsw[((bn * 4 + s) * 64 + l) * 8];
      acc = __builtin_amdgcn_mfma_f32_16x16x32_bf16(a[s], blo, acc, 0, 0, 0);
      acc = __builtin_amdgcn_mfma_f32_16x16x32_bf16(a[s], bhi, acc, 0, 0, 0);
    }
    const int col = bn * 16 + (l & 15);
#pragma unroll
    for (int i = 0; i < 4; i++) {
      int row = orow0 + i;
      if (row < NN) Z[(size_t)row * D + col] = f2bf(acc[i]);
    }
  }
}

// ---------------- layer-1 gather, batched: grid (6250, NS) ----------------
__global__ __launch_bounds__(256) void gather1_all_k(
    const unsigned short* __restrict__ H, const int* __restrict__ offsA,
    const int* __restrict__ cntA, const int2* __restrict__ eeA,
    const float* __restrict__ dinvA, const float* __restrict__ bias,
    const float* __restrict__ pa, unsigned short* __restrict__ ZhA) {
  const int t = blockIdx.y;
  int g = blockIdx.x * 256 + threadIdx.x;
  int wid = g >> 5;
  int lane = g & 31;
  if (wid >= NN) return;
  const int base = t * NN + wid;
  const int st = offsA[base];
  const int len = cntA[base];
  const int c = lane * 4;
  float ax = 0.f, ay = 0.f, az = 0.f, aw = 0.f;
  int j = 0;
  for (; j + 8 <= len; j += 8) {
    int2 p0 = eeA[st + j];
    int2 p1 = eeA[st + j + 1];
    int2 p2 = eeA[st + j + 2];
    int2 p3 = eeA[st + j + 3];
    int2 p4 = eeA[st + j + 4];
    int2 p5 = eeA[st + j + 5];
    int2 p6 = eeA[st + j + 6];
    int2 p7 = eeA[st + j + 7];
    ushort4 v0 = *(const ushort4*)&H[(size_t)p0.x * D + c];
    ushort4 v1 = *(const ushort4*)&H[(size_t)p1.x * D + c];
    ushort4 v2 = *(const ushort4*)&H[(size_t)p2.x * D + c];
    ushort4 v3 = *(const ushort4*)&H[(size_t)p3.x * D + c];
    ushort4 v4 = *(const ushort4*)&H[(size_t)p4.x * D + c];
    ushort4 v5 = *(const ushort4*)&H[(size_t)p5.x * D + c];
    ushort4 v6 = *(const ushort4*)&H[(size_t)p6.x * D + c];
    ushort4 v7 = *(const ushort4*)&H[(size_t)p7.x * D + c];
    float w0 = __int_as_float(p0.y), w1 = __int_as_float(p1.y);
    float w2 = __int_as_float(p2.y), w3 = __int_as_float(p3.y);
    float w4 = __int_as_float(p4.y), w5 = __int_as_float(p5.y);
    float w6 = __int_as_float(p6.y), w7 = __int_as_float(p7.y);
    ax += w0 * bf2f(v0.x) + w1 * bf2f(v1.x) + w2 * bf2f(v2.x) + w3 * bf2f(v3.x);
    ay += w0 * bf2f(v0.y) + w1 * bf2f(v1.y) + w2 * bf2f(v2.y) + w3 * bf2f(v3.y);
    az += w0 * bf2f(v0.z) + w1 * bf2f(v1.z) + w2 * bf2f(v2.z) + w3 * bf2f(v3.z);
    aw += w0 * bf2f(v0.w) + w1 * bf2f(v1.w) + w2 * bf2f(v2.w) + w3 * bf2f(v3.w);
    ax += w4 * bf2f(v4.x) + w5 * bf2f(v5.x) + w6 * bf2f(v6.x) + w7 * bf2f(v7.x);
    ay += w4 * bf2f(v4.y) + w5 * bf2f(v5.y) + w6 * bf2f(v6.y) + w7 * bf2f(v7.y);
    az += w4 * bf2f(v4.z) + w5 * bf2f(v5.z) + w6 * bf2f(v6.z) + w7 * bf2f(v7.z);
    aw += w4 * bf2f(v4.w) + w5 * bf2f(v5.w) + w6 * bf2f(v6.w) + w7 * bf2f(v7.w);
  }
  for (; j + 4 <= len; j += 4) {
    int2 p0 = eeA[st + j];
    int2 p1 = eeA[st + j + 1];
    int2 p2 = eeA[st + j + 2];
    int2 p3 = eeA[st + j + 3];
    ushort4 v0 = *(const ushort4*)&H[(size_t)p0.x * D + c];
    ushort4 v1 = *(const ushort4*)&H[(size_t)p1.x * D + c];
    ushort4 v2 = *(const ushort4*)&H[(size_t)p2.x * D + c];
    ushort4 v3 = *(const ushort4*)&H[(size_t)p3.x * D + c];
    float w0 = __int_as_float(p0.y), w1 = __int_as_float(p1.y);
    float w2 = __int_as_float(p2.y), w3 = __int_as_float(p3.y);
    ax += w0 * bf2f(v0.x) + w1 * bf2f(v1.x) + w2 * bf2f(v2.x) + w3 * bf2f(v3.x);
    ay += w0 * bf2f(v0.y) + w1 * bf2f(v1.y) + w2 * bf2f(v2.y) + w3 * bf2f(v3.y);
    az += w0 * bf2f(v0.z) + w1 * bf2f(v1.z) + w2 * bf2f(v2.z) + w3 * bf2f(v3.z);
    aw += w0 * bf2f(v0.w) + w1 * bf2f(v1.w) + w2 * bf2f(v2.w) + w3 * bf2f(v3.w);
  }
  for (; j < len; j++) {
    int2 p = eeA[st + j];
    float w = __int_as_float(p.y);
    ushort4 v = *(const ushort4*)&H[(size_t)p.x * D + c];
    ax += w * bf2f(v.x);
    ay += w * bf2f(v.y);
    az += w * bf2f(v.z);
    aw += w * bf2f(v.w);
  }
  float dv = dinvA[base];
  float d2 = dv * dv;
  ushort4 h = *(const ushort4*)&H[(size_t)wid * D + c];
  ax += d2 * bf2f(h.x) + bias[c];
  ay += d2 * bf2f(h.y) + bias[c + 1];
  az += d2 * bf2f(h.z) + bias[c + 2];
  aw += d2 * bf2f(h.w) + bias[c + 3];
  ax = ax > 0.f ? ax : pa[c] * ax;
  ay = ay > 0.f ? ay : pa[c + 1] * ay;
  az = az > 0.f ? az : pa[c + 2] * az;
  aw = aw > 0.f ? aw : pa[c + 3] * aw;
  ushort4 o;
  o.x = f2bf(ax); o.y = f2bf(ay); o.z = f2bf(az); o.w = f2bf(aw);
  *(ushort4*)&ZhA[(size_t)t * NN * D + (size_t)wid * D + c] = o;
}

// ---------------- layer-2 gather, batched: grid (6250, NS) ----------------
__global__ __launch_bounds__(256) void gather2_all_k(
    const unsigned short* __restrict__ YA, const int* __restrict__ offsA,
    const int* __restrict__ cntA, const int2* __restrict__ eeA,
    const float* __restrict__ dinvA, const float* __restrict__ bias,
    const float* __restrict__ pa, float* __restrict__ out) {
  const int t = blockIdx.y;
  int g = blockIdx.x * 256 + threadIdx.x;
  int wid = g >> 5;
  int lane = g & 31;
  if (wid >= NN) return;
  const unsigned short* Y = YA + (size_t)t * NN * D;
  const int base = t * NN + wid;
  const int st = offsA[base];
  const int len = cntA[base];
  const int c = lane * 4;
  float ax = 0.f, ay = 0.f, az = 0.f, aw = 0.f;
  int j = 0;
  for (; j + 8 <= len; j += 8) {
    int2 p0 = eeA[st + j];
    int2 p1 = eeA[st + j + 1];
    int2 p2 = eeA[st + j + 2];
    int2 p3 = eeA[st + j + 3];
    int2 p4 = eeA[st + j + 4];
    int2 p5 = eeA[st + j + 5];
    int2 p6 = eeA[st + j + 6];
    int2 p7 = eeA[st + j + 7];
    ushort4 v0 = *(const ushort4*)&Y[(size_t)p0.x * D + c];
    ushort4 v1 = *(const ushort4*)&Y[(size_t)p1.x * D + c];
    ushort4 v2 = *(const ushort4*)&Y[(size_t)p2.x * D + c];
    ushort4 v3 = *(const ushort4*)&Y[(size_t)p3.x * D + c];
    ushort4 v4 = *(const ushort4*)&Y[(size_t)p4.x * D + c];
    ushort4 v5 = *(const ushort4*)&Y[(size_t)p5.x * D + c];
    ushort4 v6 = *(const ushort4*)&Y[(size_t)p6.x * D + c];
    ushort4 v7 = *(const ushort4*)&Y[(size_t)p7.x * D + c];
    float w0 = __int_as_float(p0.y), w1 = __int_as_float(p1.y);
    float w2 = __int_as_float(p2.y), w3 = __int_as_float(p3.y);
    float w4 = __int_as_float(p4.y), w5 = __int_as_float(p5.y);
    float w6 = __int_as_float(p6.y), w7 = __int_as_float(p7.y);
    ax += w0 * bf2f(v0.x) + w1 * bf2f(v1.x) + w2 * bf2f(v2.x) + w3 * bf2f(v3.x);
    ay += w0 * bf2f(v0.y) + w1 * bf2f(v1.y) + w2 * bf2f(v2.y) + w3 * bf2f(v3.y);
    az += w0 * bf2f(v0.z) + w1 * bf2f(v1.z) + w2 * bf2f(v2.z) + w3 * bf2f(v3.z);
    aw += w0 * bf2f(v0.w) + w1 * bf2f(v1.w) + w2 * bf2f(v2.w) + w3 * bf2f(v3.w);
    ax += w4 * bf2f(v4.x) + w5 * bf2f(v5.x) + w6 * bf2f(v6.x) + w7 * bf2f(v7.x);
    ay += w4 * bf2f(v4.y) + w5 * bf2f(v5.y) + w6 * bf2f(v6.y) + w7 * bf2f(v7.y);
    az += w4 * bf2f(v4.z) + w5 * bf2f(v5.z) + w6 * bf2f(v6.z) + w7 * bf2f(v7.z);
    aw += w4 * bf2f(v4.w) + w5 * bf2f(v5.w) + w6 * bf2f(v6.w) + w7 * bf2f(v7.w);
  }
  for (; j + 4 <= len; j += 4) {
    int2 p0 = eeA[st + j];
    int2 p1 = eeA[st + j + 1];
    int2 p2 = eeA[st + j + 2];
    int2 p3 = eeA[st + j + 3];
    ushort4 v0 = *(const ushort4*)&Y[(size_t)p0.x * D + c];
    ushort4 v1 = *(const ushort4*)&Y[(size_t)p1.x * D + c];
    ushort4 v2 = *(const ushort4*)&Y[(size_t)p2.x * D + c];
    ushort4 v3 = *(const ushort4*)&Y[(size_t)p3.x * D + c];
    float w0 = __int_as_float(p0.y), w1 = __int_as_float(p1.y);
    float w2 = __int_as_float(p2.y), w3 = __int_as_float(p3.y);
    ax += w0 * bf2f(v0.x) + w1 * bf2f(v1.x) + w2 * bf2f(v2.x) + w3 * bf2f(v3.x);
    ay += w0 * bf2f(v0.y) + w1 * bf2f(v1.y) + w2 * bf2f(v2.y) + w3 * bf2f(v3.y);
    az += w0 * bf2f(v0.z) + w1 * bf2f(v1.z) + w2 * bf2f(v2.z) + w3 * bf2f(v3.z);
    aw += w0 * bf2f(v0.w) + w1 * bf2f(v1.w) + w2 * bf2f(v2.w) + w3 * bf2f(v3.w);
  }
  for (; j < len; j++) {
    int2 p = eeA[st + j];
    float w = __int_as_float(p.y);
    ushort4 v = *(const ushort4*)&Y[(size_t)p.x * D + c];
    ax += w * bf2f(v.x);
    ay += w * bf2f(v.y);
    az += w * bf2f(v.z);
    aw += w * bf2f(v.w);
  }
  float dv = dinvA[base];
  float d2 = dv * dv;
  ushort4 h = *(const ushort4*)&Y[(size_t)wid * D + c];
  ax += d2 * bf2f(h.x) + bias[c];
  ay += d2 * bf2f(h.y) + bias[c + 1];
  az += d2 * bf2f(h.z) + bias[c + 2];
  aw += d2 * bf2f(h.w) + bias[c + 3];
  ax = ax > 0.f ? ax : pa[c] * ax;
  ay = ay > 0.f ? ay : pa[c + 1] * ay;
  az = az > 0.f ? az : pa[c + 2] * az;
  aw = aw > 0.f ? aw : pa[c + 3] * aw;
  float* outT = out + (size_t)t * NN * D;
  *(float4*)&outT[(size_t)wid * D + c] = make_float4(ax, ay, az, aw);
}

// ---------------- launch ----------------

extern "C" void kernel_launch(void* const* d_in, const int* in_sizes, int n_in,
                              void* d_out, int out_size, void* d_ws, size_t ws_size,
                              hipStream_t stream) {
  const float* x = (const float*)d_in[0];
  const int* ei = (const int*)d_in[1];       // [4][2][NE] int32
  const float* ew = (const float*)d_in[2];   // [4][NE]
  const float* W0 = (const float*)d_in[3];
  const float* b0 = (const float*)d_in[4];
  const float* W1 = (const float*)d_in[5];
  const float* b1 = (const float*)d_in[6];
  const float* pa = (const float*)d_in[7];
  float* out = (float*)d_out;                // [4][NN][D] fp32

  // ws layout. ebin/ghist/bincnt/binbase alias the head of ZhA: all dead after
  // bincsr_k/scat_k; ZhA is written by gather1 afterwards.
  int2* eeA = (int2*)d_ws;                                // NS*NE int2  (25.6 MB)
  float* dinvA = (float*)(eeA + (size_t)NS * NE);         // NT f32
  int* cntA = (int*)(dinvA + NT);                         // NT
  int* offsA = cntA + NT;                                 // NT
  unsigned short* H0h = (unsigned short*)(offsA + NT);    // NN*D bf16 (12.8 MB)
  unsigned short* ZhA = H0h + (size_t)NN * D;             // NS*NN*D bf16 (51.2 MB)
  unsigned short* Wsw = ZhA + (size_t)NS * NN * D;        // 32768 ushorts (64 KB)
  int2* ebin = (int2*)ZhA;                                // alias: NS*NE int2
  u32* ghist = (u32*)(ebin + (size_t)NS * NE);            // alias: NS*NB*CB u32
  u32* bincnt = ghist + (size_t)NS * NB * CB;             // alias: NS*NB
  u32* binbase = bincnt + NS * NB;                        // alias: NS*NB

  const int gGemm = (NN + 63) / 64;           // 782
  const int gEdge = (NE + 255) / 256;         // 3125
  const int gGather = (NN * 32 + 255) / 256;  // 6250
  const int gFused = CB + CB + 64;            // hist + gemm + prep

  // CSR build: counting sort by dst (LDS atomics only; zero global atomics)
  fused_hg_k<<<dim3(gFused, NS), 256, 0, stream>>>(ei, ghist, x, W0, H0h, W1, Wsw);
  scanbin_k<<<dim3(NB, NS), 256, 0, stream>>>(ghist, bincnt);
  binbase_k<<<dim3(1, NS), 256, 0, stream>>>(bincnt, binbase);
  scat_k<<<dim3(CB, NS), 256, 0, stream>>>(ei, ew, ghist, binbase, ebin);
  bincsr_k<<<dim3(NB, NS), 256, 0, stream>>>(ebin, bincnt, binbase, cntA, offsA,
                                             dinvA, eeA);
  rescale_k<<<dim3(gEdge, NS), 256, 0, stream>>>(dinvA, eeA);

  // layer 1 (all scales): ZhA[t] = bf16(prelu(Agg_t(H0h) + b0))
  gather1_all_k<<<dim3(gGather, NS), 256, 0, stream>>>(H0h, offsA, cntA, eeA,
                                                       dinvA, b0, pa, ZhA);
  // layer 2, commuted: Y = Zh@W1 (in-place, MFMA), then out = prelu(Agg_t(Y)+b1)
  gemm_inplace_mfma_k<<<dim3(gGemm, NS), 256, 0, stream>>>(ZhA, Wsw);
  gather2_all_k<<<dim3(gGather, NS), 256, 0, stream>>>(ZhA, offsA, cntA, eeA,
                                                       dinvA, b1, pa, out);
}